// Round 15
// baseline (85.314 us; speedup 1.0000x reference)
//
#include <hip/hip_runtime.h>

namespace {
constexpr int N   = 64;
constexpr int D   = 32;
constexpr int PD  = 36;   // padded ind row (dwords): measured conflict-free (r1/r2)
constexpr int SHP = 104;  // sh row pad: >=64 payload (r10 lesson); 104%32==8
                          // conflict-free (r11-r14). LDS 41728 B -> 3-blocks/CU
                          // window -> compiler VGPR target 85 (r4-r6 spill trap
                          // fires in the <=40.96 KB window with target 64).
constexpr float LOG2E = 1.4426950408889634f;
constexpr float LN2   = 0.6931471805599453f;

typedef float f32x2 __attribute__((ext_vector_type(2)));

#if __has_builtin(__builtin_amdgcn_exp2f)
__device__ __forceinline__ float fexp2(float x) { return __builtin_amdgcn_exp2f(x); }
#else
__device__ __forceinline__ float fexp2(float x) { return exp2f(x); }
#endif
#if __has_builtin(__builtin_amdgcn_rcpf)
__device__ __forceinline__ float frcp(float x) { return __builtin_amdgcn_rcpf(x); }
#else
__device__ __forceinline__ float frcp(float x) { return 1.0f / x; }
#endif
__device__ __forceinline__ void wavebar() {
#if __has_builtin(__builtin_amdgcn_wave_barrier)
    __builtin_amdgcn_wave_barrier();
#endif
}

// Grid 1024 = 2 blocks per b (32 i-rows each), block 512 (8 waves).
// r15: LDS-PIPE RELIEF. Cycle model (b128=12cyc): post-barrier LDS stream was
// ~1.9K cyc/wave x 24 waves/CU ~ 19us/CU -- the dominant serializer (VALU only
// ~7.5us/SIMD). The gate block (40 b128 = 480 cyc/wave, 25%) moves PRE-BARRIER
// fed from GLOBAL: its VMEM reads overlap the staging loads' latency bubble
// (unlike r8, which put global broadcasts in the hot loop and serialized).
// Post-barrier structure identical to r14: sign-split packed score loop,
// 4-way-ILP softmax, barrier-free phase 2 (same-wave sh rows).
// Single-exp identity (exact):
//   elup1(a)*elup1(b) = exp2(min(aL,0)+min(bL,0)) * (1+max(aL,0)*ln2) * (1+max(bL,0)*ln2)
__global__ __launch_bounds__(512, 4) void fused(
        const float* __restrict__ feature,
        const float* __restrict__ ind,
        float* __restrict__ out) {
    __shared__ float ind_lds[3][N][PD];   // 27648 B
    __shared__ float s_lds[3][N];         //   768 B
    __shared__ float sh_lds[32][SHP];     // 13312 B   total 41728 B -> 3 blocks/CU

    const int t      = threadIdx.x;
    const int lane   = t & 63;
    const int wave   = t >> 6;
    const int blk    = blockIdx.x;
    const int b      = blk >> 1;
    const int i_base = (blk & 1) << 5;

    // ---- stage indicator: 1536 float4, 3 per thread, coalesced ----
    {
        const float4* src = reinterpret_cast<const float4*>(ind);
#pragma unroll
        for (int idx = t; idx < 3 * N * D / 4; idx += 512) {
            int a = idx >> 9;
            int r = idx & 511;
            int n = r >> 3;
            int k = r & 7;
            *reinterpret_cast<float4*>(&ind_lds[a][n][k * 4]) = src[idx];
        }
    }

    // ---- s[a][n] = feature[b,n,:] . ind[a,n,:] from GLOBAL, overlapped with
    //      staging (merges old barrier 2 into barrier 1; r13-verified) ----
    if (t < 3 * N) {
        int a = t >> 6, n = t & 63;
        const float4* frow = reinterpret_cast<const float4*>(feature + ((size_t)b * N + n) * D);
        const float4* irow = reinterpret_cast<const float4*>(ind + (a * N + n) * D);
        f32x2 sa2 = {0.f, 0.f};
#pragma unroll
        for (int k = 0; k < 8; ++k) {
            float4 f4 = frow[k];
            float4 i4 = irow[k];
            sa2 = __builtin_elementwise_fma(f32x2{f4.x, f4.y}, f32x2{i4.x, i4.y}, sa2);
            sa2 = __builtin_elementwise_fma(f32x2{f4.z, f4.w}, f32x2{i4.z, i4.w}, sa2);
        }
        s_lds[a][n] = sa2.x + sa2.y;
    }

    // ---- gate bitmasks PRE-BARRIER from GLOBAL (overlaps staging latency;
    //      removes 40 b128/wave from the post-barrier LDS stream) ----
    // gate[ig][lane] = 1[ ind0[ig,:] . ind1[lane,:] > 0 ]
    unsigned long long gmask[4];
    {
        const float4* i0g = reinterpret_cast<const float4*>(ind);          // [N][8]
        const float4* i1g = reinterpret_cast<const float4*>(ind + N * D);  // [N][8]
        float4 w4k[8];
#pragma unroll
        for (int k = 0; k < 8; ++k) w4k[k] = i1g[lane * 8 + k];            // coalesced
        f32x2 ga[4] = {{0.f, 0.f}, {0.f, 0.f}, {0.f, 0.f}, {0.f, 0.f}};
#pragma unroll
        for (int k = 0; k < 8; ++k) {
            f32x2 wp0 = {w4k[k].x, w4k[k].y}, wp1 = {w4k[k].z, w4k[k].w};
#pragma unroll
            for (int r = 0; r < 4; ++r) {
                float4 a4 = i0g[(i_base + wave * 4 + r) * 8 + k];          // broadcast (L1-hot)
                ga[r] = __builtin_elementwise_fma(f32x2{a4.x, a4.y}, wp0, ga[r]);
                ga[r] = __builtin_elementwise_fma(f32x2{a4.z, a4.w}, wp1, ga[r]);
            }
        }
#pragma unroll
        for (int r = 0; r < 4; ++r) gmask[r] = __ballot(ga[r].x + ga[r].y > 0.f);
    }
    __syncthreads();   // the ONLY block barrier

    const float s1Ls = s_lds[1][lane] * LOG2E;
    const f32x2 s1L  = {s1Ls, s1Ls};
    const f32x2 ln2v = {LN2, LN2};
    const f32x2 onev = {1.0f, 1.0f};
    const f32x2 zerv = {0.0f, 0.0f};

    // ---- hoisted row scalars ----
    float s0v[4];
#pragma unroll
    for (int r = 0; r < 4; ++r) s0v[r] = s_lds[0][i_base + wave * 4 + r] * LOG2E;

    // ---- score: sign-split packed loop, 2 chunks of 16 d-elements (r14) ----
    f32x2 sc2[4] = {{0.f, 0.f}, {0.f, 0.f}, {0.f, 0.f}, {0.f, 0.f}};

#define SCORE_BODY(NEGA, FMAA, AM, FM)                                              \
    {                                                                               \
        const f32x2 amv = {(AM), (AM)};                                             \
        const f32x2 fmv = {(FM), (FM)};                                             \
        f32x2 acc = sc2[r];                                                         \
        _Pragma("unroll")                                                           \
        for (int k4 = 0; k4 < 4; ++k4) {                                            \
            float4 v4 = *reinterpret_cast<const float4*>(                           \
                &ind_lds[1][ig][c * 16 + k4 * 4]);                                  \
            f32x2 vp[2] = {f32x2{v4.x, v4.y}, f32x2{v4.z, v4.w}};                   \
            _Pragma("unroll")                                                       \
            for (int h = 0; h < 2; ++h) {                                           \
                f32x2 aneg = amv * NEGA[k4 * 2 + h];                                \
                f32x2 A    = __builtin_elementwise_fma(fmv, FMAA[k4 * 2 + h], onev);\
                f32x2 bL   = s1L * vp[h];                                           \
                f32x2 bneg = __builtin_elementwise_min(bL, zerv);                   \
                f32x2 B    = __builtin_elementwise_fma(                             \
                    __builtin_elementwise_max(bL, zerv), ln2v, onev);               \
                f32x2 mn   = aneg + bneg;                                           \
                f32x2 E    = {fexp2(mn.x), fexp2(mn.y)};                            \
                acc = __builtin_elementwise_fma(E * A, B, acc);                     \
            }                                                                       \
        }                                                                           \
        sc2[r] = acc;                                                               \
    }

#pragma unroll
    for (int c = 0; c < 2; ++c) {
        // per-chunk precompute: un = min(u,0), upl = max(u,0)*ln2  (16 f32x2 live)
        f32x2 un[8], upl[8];
#pragma unroll
        for (int k4 = 0; k4 < 4; ++k4) {
            float4 v = *reinterpret_cast<const float4*>(&ind_lds[0][lane][c * 16 + k4 * 4]);
            f32x2 x0 = {v.x, v.y}, x1 = {v.z, v.w};
            f32x2 n0 = __builtin_elementwise_min(x0, zerv);
            f32x2 n1 = __builtin_elementwise_min(x1, zerv);
            un[k4 * 2 + 0]  = n0;
            un[k4 * 2 + 1]  = n1;
            upl[k4 * 2 + 0] = (x0 - n0) * ln2v;
            upl[k4 * 2 + 1] = (x1 - n1) * ln2v;
        }
#pragma unroll
        for (int r = 0; r < 4; ++r) {
            const int ig = i_base + wave * 4 + r;
            // force wave-uniform scalar: s_cmp + s_cbranch, zero divergence
            const float s0u = __uint_as_float(
                __builtin_amdgcn_readfirstlane(__float_as_uint(s0v[r])));
            if (s0u >= 0.f) {
                SCORE_BODY(un, upl, s0u, s0u)
            } else {
                SCORE_BODY(upl, un, s0u * LOG2E, s0u * LN2)
            }
        }
    }
#undef SCORE_BODY

    float score[4];
#pragma unroll
    for (int r = 0; r < 4; ++r) score[r] = sc2[r].x + sc2[r].y;

    // ---- 4-way-ILP wave softmax over j (64 lanes) ----
    float mx[4], e[4], sm[4];
#pragma unroll
    for (int r = 0; r < 4; ++r) mx[r] = score[r];
#pragma unroll
    for (int off = 32; off >= 1; off >>= 1) {
#pragma unroll
        for (int r = 0; r < 4; ++r) mx[r] = fmaxf(mx[r], __shfl_xor(mx[r], off));
    }
#pragma unroll
    for (int r = 0; r < 4; ++r) e[r] = fexp2((score[r] - mx[r]) * LOG2E);
#pragma unroll
    for (int r = 0; r < 4; ++r) sm[r] = e[r];
#pragma unroll
    for (int off = 32; off >= 1; off >>= 1) {
#pragma unroll
        for (int r = 0; r < 4; ++r) sm[r] += __shfl_xor(sm[r], off);
    }
#pragma unroll
    for (int r = 0; r < 4; ++r) {
        const int ig    = i_base + wave * 4 + r;
        const int i_loc = wave * 4 + r;
        const float g   = (float)((gmask[r] >> lane) & 1ull);
        sh_lds[i_loc][lane] = (e[r] * g) * (s_lds[2][ig] * frcp(sm[r]));
    }

    // NO block barrier: wave w wrote sh rows 4w..4w+3 and reads only those
    // rows below (same-wave LDS RAW, lgkmcnt-ordered; r13/r14-verified).
    wavebar();

    // ---- phase 2: out[i,:] = sh[i,:] @ ind2; thread = (i_loc, d-quad, j-half) ----
    {
        const int i_loc = t >> 4;
        const int sub   = t & 15;
        const int dq    = sub & 7;
        const int jh    = sub >> 3;
        f32x2 acc0 = {0.f, 0.f}, acc1 = {0.f, 0.f};
#pragma unroll
        for (int jj = 0; jj < 32; jj += 4) {
            int j = jh * 32 + jj;
            float4 sh4 = *reinterpret_cast<const float4*>(&sh_lds[i_loc][j]);
#pragma unroll
            for (int c = 0; c < 4; ++c) {
                float4 v4 = *reinterpret_cast<const float4*>(&ind_lds[2][j + c][dq * 4]);
                float  w  = (&sh4.x)[c];
                f32x2 wv = {w, w};
                acc0 = __builtin_elementwise_fma(wv, f32x2{v4.x, v4.y}, acc0);
                acc1 = __builtin_elementwise_fma(wv, f32x2{v4.z, v4.w}, acc1);
            }
        }
        float4 acc = {acc0.x, acc0.y, acc1.x, acc1.y};
        acc.x += __shfl_xor(acc.x, 8);   // combine j-halves (lanes t, t^8)
        acc.y += __shfl_xor(acc.y, 8);
        acc.z += __shfl_xor(acc.z, 8);
        acc.w += __shfl_xor(acc.w, 8);
        if (jh == 0) {
            *reinterpret_cast<float4*>(out + ((size_t)b * N + i_base + i_loc) * D + dq * 4) = acc;
        }
    }
}
}  // namespace

extern "C" void kernel_launch(void* const* d_in, const int* in_sizes, int n_in,
                              void* d_out, int out_size, void* d_ws, size_t ws_size,
                              hipStream_t stream) {
    const float* feature = (const float*)d_in[0];
    const float* ind     = (const float*)d_in[1];
    float*       out     = (float*)d_out;
    fused<<<1024, 512, 0, stream>>>(feature, ind, out);
}

// Round 16
// 79.389 us; speedup vs baseline: 1.0746x; 1.0746x over previous
//
#include <hip/hip_runtime.h>

namespace {
constexpr int N   = 64;
constexpr int D   = 32;
constexpr int PD  = 36;   // padded ind row (dwords): measured conflict-free (r1/r2)
constexpr int SHP = 104;  // sh row pad: >=64 payload (r10 lesson); 104%32==8
                          // conflict-free (r11-r14). LDS 41728 B -> 3-blocks/CU
                          // window -> compiler VGPR target 85 (r4-r6 spill trap
                          // fires in the <=40.96 KB window with target 64).
constexpr float LOG2E = 1.4426950408889634f;
constexpr float LN2   = 0.6931471805599453f;

typedef float f32x2 __attribute__((ext_vector_type(2)));

#if __has_builtin(__builtin_amdgcn_exp2f)
__device__ __forceinline__ float fexp2(float x) { return __builtin_amdgcn_exp2f(x); }
#else
__device__ __forceinline__ float fexp2(float x) { return exp2f(x); }
#endif
#if __has_builtin(__builtin_amdgcn_rcpf)
__device__ __forceinline__ float frcp(float x) { return __builtin_amdgcn_rcpf(x); }
#else
__device__ __forceinline__ float frcp(float x) { return 1.0f / x; }
#endif
__device__ __forceinline__ void wavebar() {
#if __has_builtin(__builtin_amdgcn_wave_barrier)
    __builtin_amdgcn_wave_barrier();
#endif
}

// Grid 1024 = 2 blocks per b (32 i-rows each), block 512 (8 waves). r14 base
// (single barrier, packed fp32, sign-split score, barrier-free phase 2) + r16:
// SCALAR-PIPE BROADCASTS. The 64 wave-uniform b128 row reads per wave (gate a4
// + score v4) move off the LDS pipe onto s_load: row index forced uniform via
// readfirstlane -> compiler emits s_load_dwordx4 from global ind (K$/L2-hot),
// SGPR operands fold into v_pk_*. Post-barrier LDS stream -40%.
// r15 LESSON: the same traffic as VECTOR-pipe global loads pre-barrier
// regressed 4.6us (vmcnt(0) drain before s_barrier); scalar pipe + post-barrier
// placement avoids both failure modes (r8, r15).
// Single-exp identity (exact):
//   elup1(a)*elup1(b) = exp2(min(aL,0)+min(bL,0)) * (1+max(aL,0)*ln2) * (1+max(bL,0)*ln2)
__global__ __launch_bounds__(512, 4) void fused(
        const float* __restrict__ feature,
        const float* __restrict__ ind,
        float* __restrict__ out) {
    __shared__ float ind_lds[3][N][PD];   // 27648 B
    __shared__ float s_lds[3][N];         //   768 B
    __shared__ float sh_lds[32][SHP];     // 13312 B   total 41728 B -> 3 blocks/CU

    const int t      = threadIdx.x;
    const int lane   = t & 63;
    const int wave   = t >> 6;
    const int blk    = blockIdx.x;
    const int b      = blk >> 1;
    const int i_base = (blk & 1) << 5;

    // ---- stage indicator: 1536 float4, 3 per thread, coalesced ----
    {
        const float4* src = reinterpret_cast<const float4*>(ind);
#pragma unroll
        for (int idx = t; idx < 3 * N * D / 4; idx += 512) {
            int a = idx >> 9;
            int r = idx & 511;
            int n = r >> 3;
            int k = r & 7;
            *reinterpret_cast<float4*>(&ind_lds[a][n][k * 4]) = src[idx];
        }
    }

    // ---- s[a][n] = feature[b,n,:] . ind[a,n,:] from GLOBAL, overlapped with
    //      staging (merges old barrier 2 into barrier 1; r13-verified) ----
    if (t < 3 * N) {
        int a = t >> 6, n = t & 63;
        const float4* frow = reinterpret_cast<const float4*>(feature + ((size_t)b * N + n) * D);
        const float4* irow = reinterpret_cast<const float4*>(ind + (a * N + n) * D);
        f32x2 sa2 = {0.f, 0.f};
#pragma unroll
        for (int k = 0; k < 8; ++k) {
            float4 f4 = frow[k];
            float4 i4 = irow[k];
            sa2 = __builtin_elementwise_fma(f32x2{f4.x, f4.y}, f32x2{i4.x, i4.y}, sa2);
            sa2 = __builtin_elementwise_fma(f32x2{f4.z, f4.w}, f32x2{i4.z, i4.w}, sa2);
        }
        s_lds[a][n] = sa2.x + sa2.y;
    }
    __syncthreads();   // the ONLY block barrier

    // wave-uniform row indices (readfirstlane -> SGPR -> s_load addresses)
    int igu[4];
#pragma unroll
    for (int r = 0; r < 4; ++r)
        igu[r] = __builtin_amdgcn_readfirstlane(i_base + wave * 4 + r);

    // ---- gate bitmasks (post-barrier, r14 position): a4 rows via SCALAR loads
    //      from global ind0 (wave-uniform addr); lane reads stay in LDS ----
    unsigned long long gmask[4];
    {
        f32x2 ga[4] = {{0.f, 0.f}, {0.f, 0.f}, {0.f, 0.f}, {0.f, 0.f}};
#pragma unroll
        for (int k = 0; k < 8; ++k) {
            float4 w4 = *reinterpret_cast<const float4*>(&ind_lds[1][lane][k * 4]);  // lane read
            f32x2 wp0 = {w4.x, w4.y}, wp1 = {w4.z, w4.w};
#pragma unroll
            for (int r = 0; r < 4; ++r) {
                float4 a4 = *reinterpret_cast<const float4*>(ind + igu[r] * D + k * 4);  // s_load
                ga[r] = __builtin_elementwise_fma(f32x2{a4.x, a4.y}, wp0, ga[r]);
                ga[r] = __builtin_elementwise_fma(f32x2{a4.z, a4.w}, wp1, ga[r]);
            }
        }
#pragma unroll
        for (int r = 0; r < 4; ++r) gmask[r] = __ballot(ga[r].x + ga[r].y > 0.f);
    }

    const float s1Ls = s_lds[1][lane] * LOG2E;
    const f32x2 s1L  = {s1Ls, s1Ls};
    const f32x2 ln2v = {LN2, LN2};
    const f32x2 onev = {1.0f, 1.0f};
    const f32x2 zerv = {0.0f, 0.0f};

    // ---- hoisted row scalars ----
    float s0v[4];
#pragma unroll
    for (int r = 0; r < 4; ++r) s0v[r] = s_lds[0][i_base + wave * 4 + r] * LOG2E;

    // ---- score: sign-split packed loop, 2 chunks of 16 d-elements (r14);
    //      v4 rows via SCALAR loads from global ind1 (wave-uniform addr) ----
    f32x2 sc2[4] = {{0.f, 0.f}, {0.f, 0.f}, {0.f, 0.f}, {0.f, 0.f}};

#define SCORE_BODY(NEGA, FMAA, AM, FM)                                              \
    {                                                                               \
        const f32x2 amv = {(AM), (AM)};                                             \
        const f32x2 fmv = {(FM), (FM)};                                             \
        f32x2 acc = sc2[r];                                                         \
        _Pragma("unroll")                                                           \
        for (int k4 = 0; k4 < 4; ++k4) {                                            \
            float4 v4 = *reinterpret_cast<const float4*>(                           \
                ind + N * D + igu[r] * D + c * 16 + k4 * 4);   /* s_load */         \
            f32x2 vp[2] = {f32x2{v4.x, v4.y}, f32x2{v4.z, v4.w}};                   \
            _Pragma("unroll")                                                       \
            for (int h = 0; h < 2; ++h) {                                           \
                f32x2 aneg = amv * NEGA[k4 * 2 + h];                                \
                f32x2 A    = __builtin_elementwise_fma(fmv, FMAA[k4 * 2 + h], onev);\
                f32x2 bL   = s1L * vp[h];                                           \
                f32x2 bneg = __builtin_elementwise_min(bL, zerv);                   \
                f32x2 B    = __builtin_elementwise_fma(                             \
                    __builtin_elementwise_max(bL, zerv), ln2v, onev);               \
                f32x2 mn   = aneg + bneg;                                           \
                f32x2 E    = {fexp2(mn.x), fexp2(mn.y)};                            \
                acc = __builtin_elementwise_fma(E * A, B, acc);                     \
            }                                                                       \
        }                                                                           \
        sc2[r] = acc;                                                               \
    }

#pragma unroll
    for (int c = 0; c < 2; ++c) {
        // per-chunk precompute: un = min(u,0), upl = max(u,0)*ln2  (16 f32x2 live)
        f32x2 un[8], upl[8];
#pragma unroll
        for (int k4 = 0; k4 < 4; ++k4) {
            float4 v = *reinterpret_cast<const float4*>(&ind_lds[0][lane][c * 16 + k4 * 4]);
            f32x2 x0 = {v.x, v.y}, x1 = {v.z, v.w};
            f32x2 n0 = __builtin_elementwise_min(x0, zerv);
            f32x2 n1 = __builtin_elementwise_min(x1, zerv);
            un[k4 * 2 + 0]  = n0;
            un[k4 * 2 + 1]  = n1;
            upl[k4 * 2 + 0] = (x0 - n0) * ln2v;
            upl[k4 * 2 + 1] = (x1 - n1) * ln2v;
        }
#pragma unroll
        for (int r = 0; r < 4; ++r) {
            // force wave-uniform scalar: s_cmp + s_cbranch, zero divergence
            const float s0u = __uint_as_float(
                __builtin_amdgcn_readfirstlane(__float_as_uint(s0v[r])));
            if (s0u >= 0.f) {
                SCORE_BODY(un, upl, s0u, s0u)
            } else {
                SCORE_BODY(upl, un, s0u * LOG2E, s0u * LN2)
            }
        }
    }
#undef SCORE_BODY

    float score[4];
#pragma unroll
    for (int r = 0; r < 4; ++r) score[r] = sc2[r].x + sc2[r].y;

    // ---- 4-way-ILP wave softmax over j (64 lanes) ----
    float mx[4], e[4], sm[4];
#pragma unroll
    for (int r = 0; r < 4; ++r) mx[r] = score[r];
#pragma unroll
    for (int off = 32; off >= 1; off >>= 1) {
#pragma unroll
        for (int r = 0; r < 4; ++r) mx[r] = fmaxf(mx[r], __shfl_xor(mx[r], off));
    }
#pragma unroll
    for (int r = 0; r < 4; ++r) e[r] = fexp2((score[r] - mx[r]) * LOG2E);
#pragma unroll
    for (int r = 0; r < 4; ++r) sm[r] = e[r];
#pragma unroll
    for (int off = 32; off >= 1; off >>= 1) {
#pragma unroll
        for (int r = 0; r < 4; ++r) sm[r] += __shfl_xor(sm[r], off);
    }
#pragma unroll
    for (int r = 0; r < 4; ++r) {
        const int ig    = i_base + wave * 4 + r;
        const int i_loc = wave * 4 + r;
        const float g   = (float)((gmask[r] >> lane) & 1ull);
        sh_lds[i_loc][lane] = (e[r] * g) * (s_lds[2][ig] * frcp(sm[r]));
    }

    // NO block barrier: wave w wrote sh rows 4w..4w+3 and reads only those
    // rows below (same-wave LDS RAW, lgkmcnt-ordered; r13/r14-verified).
    wavebar();

    // ---- phase 2: out[i,:] = sh[i,:] @ ind2; thread = (i_loc, d-quad, j-half) ----
    {
        const int i_loc = t >> 4;
        const int sub   = t & 15;
        const int dq    = sub & 7;
        const int jh    = sub >> 3;
        f32x2 acc0 = {0.f, 0.f}, acc1 = {0.f, 0.f};
#pragma unroll
        for (int jj = 0; jj < 32; jj += 4) {
            int j = jh * 32 + jj;
            float4 sh4 = *reinterpret_cast<const float4*>(&sh_lds[i_loc][j]);
#pragma unroll
            for (int c = 0; c < 4; ++c) {
                float4 v4 = *reinterpret_cast<const float4*>(&ind_lds[2][j + c][dq * 4]);
                float  w  = (&sh4.x)[c];
                f32x2 wv = {w, w};
                acc0 = __builtin_elementwise_fma(wv, f32x2{v4.x, v4.y}, acc0);
                acc1 = __builtin_elementwise_fma(wv, f32x2{v4.z, v4.w}, acc1);
            }
        }
        float4 acc = {acc0.x, acc0.y, acc1.x, acc1.y};
        acc.x += __shfl_xor(acc.x, 8);   // combine j-halves (lanes t, t^8)
        acc.y += __shfl_xor(acc.y, 8);
        acc.z += __shfl_xor(acc.z, 8);
        acc.w += __shfl_xor(acc.w, 8);
        if (jh == 0) {
            *reinterpret_cast<float4*>(out + ((size_t)b * N + i_base + i_loc) * D + dq * 4) = acc;
        }
    }
}
}  // namespace

extern "C" void kernel_launch(void* const* d_in, const int* in_sizes, int n_in,
                              void* d_out, int out_size, void* d_ws, size_t ws_size,
                              hipStream_t stream) {
    const float* feature = (const float*)d_in[0];
    const float* ind     = (const float*)d_in[1];
    float*       out     = (float*)d_out;
    fused<<<1024, 512, 0, stream>>>(feature, ind, out);
}